// Round 1
// baseline (2584.391 us; speedup 1.0000x reference)
//
#include <hip/hip_runtime.h>

// Fused entmax(alpha=1.3) attention, fp32. B=16, N=2048, D=64.
// One wave per query row; 4 waves (4 rows) per block share K/V stream via L1.
// Scores held in 32 VGPRs/lane (element m lives in lane m%64, slot m/64).
// tau solved by 14 bisection + 4 Newton iters on bracket [-1, -1e-6]
// (mathematically equivalent fixed point to the reference's 50-iter bisection).

#define NBATCH 16
#define NSEQ   2048
#define DHEAD  64
#define OUT_OFF (NBATCH * NSEQ * DHEAD)   // out comes first, attn second
#define INV_A    3.3333333f               // 1/(alpha-1)
#define INV_A_M1 2.3333333f               // INV_A - 1

__device__ __forceinline__ float fast_log2(float x) {
#if __has_builtin(__builtin_amdgcn_logf)
    return __builtin_amdgcn_logf(x);
#else
    return __log2f(x);
#endif
}
__device__ __forceinline__ float fast_exp2(float x) {
#if __has_builtin(__builtin_amdgcn_exp2f)
    return __builtin_amdgcn_exp2f(x);
#else
    return exp2f(x);
#endif
}

__global__ __launch_bounds__(256) void entmax_attn_kernel(
    const float* __restrict__ Q, const float* __restrict__ K,
    const float* __restrict__ V, float* __restrict__ Out)
{
    __shared__ float q_lds[4][64];
    __shared__ float p_lds[4][2048];

    const int tid  = threadIdx.x;
    const int w    = tid >> 6;        // wave id 0..3
    const int lane = tid & 63;

    // XCD-pinning swizzle: batch b lives on XCD b%8 (2 batches per XCD),
    // so K/V for a batch (1 MB) stay resident in that XCD's 4 MB L2.
    const int i   = blockIdx.x;       // 0..8191
    const int xcd = i & 7;
    const int j2  = i >> 3;           // 0..1023
    const int b   = xcd + 8 * (j2 & 1);
    const int rb  = j2 >> 1;          // 0..511 row-block within batch
    const int n   = rb * 4 + w;       // this wave's query row

    const float* Kb = K + (size_t)b * NSEQ * DHEAD;
    const float* Vb = V + (size_t)b * NSEQ * DHEAD;

    // stage the block's 4 q rows
    {
        const int r = tid >> 6, d = tid & 63;
        q_lds[r][d] = Q[((size_t)b * NSEQ + (size_t)(rb * 4 + r)) * DHEAD + d];
    }
    __syncthreads();

    float4 qv[16];
    #pragma unroll
    for (int g = 0; g < 16; ++g) qv[g] = ((const float4*)q_lds[w])[g];

    // ---------------- phase 1: scores s[m] = q . k[m] / 8 ----------------
    // lane holds m = j*64 + lane. All 4 waves read identical K addresses;
    // periodic barriers keep them in lockstep for L1 reuse.
    float s[32];
    #pragma unroll 2
    for (int j = 0; j < 32; ++j) {
        const float4* kp = (const float4*)(Kb + (size_t)(j * 64 + lane) * DHEAD);
        float acc = 0.f;
        #pragma unroll
        for (int g = 0; g < 16; ++g) {
            float4 kv = kp[g];
            acc += qv[g].x * kv.x;
            acc += qv[g].y * kv.y;
            acc += qv[g].z * kv.z;
            acc += qv[g].w * kv.w;
        }
        s[j] = acc * 0.125f;
        if ((j & 3) == 3) __syncthreads();
    }

    // ---------------- phase 2: entmax over the row ----------------
    // row max (butterfly gives bitwise-identical result in all lanes)
    float mx = s[0];
    #pragma unroll
    for (int j = 1; j < 32; ++j) mx = fmaxf(mx, s[j]);
    #pragma unroll
    for (int off = 32; off >= 1; off >>= 1) mx = fmaxf(mx, __shfl_xor(mx, off, 64));
    #pragma unroll
    for (int j = 0; j < 32; ++j) s[j] -= mx;

    // bisection: root of sum(max(x-tau,0)^INV_A) = 1 lies in [-1, -1e-6]
    float lo = -1.0f, hi = -1e-6f;
    #pragma unroll 1
    for (int it = 0; it < 14; ++it) {
        const float tau = 0.5f * (lo + hi);
        float S = 0.f;
        #pragma unroll
        for (int j = 0; j < 32; ++j) {
            const float t = s[j] - tau;
            const float p = fast_exp2(INV_A * fast_log2(t));
            S += (t > 0.f) ? p : 0.f;
        }
        #pragma unroll
        for (int off = 32; off >= 1; off >>= 1) S += __shfl_xor(S, off, 64);
        if (S > 1.f) lo = tau; else hi = tau;   // uniform across wave
    }

    // Newton polish from the left bracket (monotone for convex decreasing g)
    float tau = lo;
    #pragma unroll 1
    for (int it = 0; it < 4; ++it) {
        float S1 = 0.f, S2 = 0.f;
        #pragma unroll
        for (int j = 0; j < 32; ++j) {
            const float t  = s[j] - tau;
            const float l2 = fast_log2(t);
            const float p  = fast_exp2(INV_A * l2);
            const float pd = fast_exp2(INV_A_M1 * l2);   // p / t, no rcp
            const bool pos = (t > 0.f);
            S1 += pos ? p  : 0.f;
            S2 += pos ? pd : 0.f;
        }
        #pragma unroll
        for (int off = 32; off >= 1; off >>= 1) {
            S1 += __shfl_xor(S1, off, 64);
            S2 += __shfl_xor(S2, off, 64);
        }
        tau += (S1 - 1.f) / (INV_A * S2);
        tau = fmaxf(fminf(tau, hi), lo);
    }

    // final probabilities + normalization
    float S = 0.f;
    #pragma unroll
    for (int j = 0; j < 32; ++j) {
        const float t = s[j] - tau;
        const float p = (t > 0.f) ? fast_exp2(INV_A * fast_log2(t)) : 0.f;
        s[j] = p;
        S += p;
    }
    #pragma unroll
    for (int off = 32; off >= 1; off >>= 1) S += __shfl_xor(S, off, 64);
    const float rnorm = 1.f / (S + 1e-12f);

    // write attn row (coalesced 256B/wave-instr) + stash in LDS for PV
    float* attn_row = Out + OUT_OFF + (size_t)(b * NSEQ + n) * NSEQ;
    #pragma unroll
    for (int j = 0; j < 32; ++j) {
        const float pv = s[j] * rnorm;
        attn_row[j * 64 + lane] = pv;
        p_lds[w][j * 64 + lane] = pv;
    }
    __syncthreads();

    // ---------------- phase 3: out[d] = sum_m p[m] * v[m][d] ----------------
    // lane = msub*16 + d4: 4 m-rows x 16 float4 lanes = 1 KB fully coalesced.
    const int msub = lane >> 4;
    const int d4   = lane & 15;
    float4 acc = make_float4(0.f, 0.f, 0.f, 0.f);
    const float* vb = Vb + (size_t)msub * DHEAD + (size_t)d4 * 4;
    const float* pw = p_lds[w] + msub;
    #pragma unroll 4
    for (int m0 = 0; m0 < 2048; m0 += 4) {
        const float  pv = pw[m0];                       // LDS broadcast x4
        const float4 vv = *(const float4*)(vb + (size_t)m0 * DHEAD);
        acc.x += pv * vv.x;
        acc.y += pv * vv.y;
        acc.z += pv * vv.z;
        acc.w += pv * vv.w;
        if ((m0 & 255) == 252) __syncthreads();         // keep waves on same V stream
    }
    #pragma unroll
    for (int off = 16; off <= 32; off <<= 1) {
        acc.x += __shfl_xor(acc.x, off, 64);
        acc.y += __shfl_xor(acc.y, off, 64);
        acc.z += __shfl_xor(acc.z, off, 64);
        acc.w += __shfl_xor(acc.w, off, 64);
    }
    if (msub == 0) {
        *(float4*)(Out + (size_t)(b * NSEQ + n) * DHEAD + (size_t)d4 * 4) = acc;
    }
}

extern "C" void kernel_launch(void* const* d_in, const int* in_sizes, int n_in,
                              void* d_out, int out_size, void* d_ws, size_t ws_size,
                              hipStream_t stream) {
    const float* q = (const float*)d_in[0];
    const float* k = (const float*)d_in[1];
    const float* v = (const float*)d_in[2];
    float* out = (float*)d_out;
    (void)in_sizes; (void)n_in; (void)out_size; (void)d_ws; (void)ws_size;
    dim3 grid(8192), block(256);
    hipLaunchKernelGGL(entmax_attn_kernel, grid, block, 0, stream, q, k, v, out);
}

// Round 2
// 1160.719 us; speedup vs baseline: 2.2265x; 2.2265x over previous
//
#include <hip/hip_runtime.h>

// Fused entmax(alpha=1.3) attention, fp32. B=16, N=2048, D=64.
// R2: K staged in LDS (coalesced global -> b128 LDS reads at 8-phase floor),
// 2 q-rows per wave (K LDS traffic halved), q via LDS broadcast reads.
// LDS union: K tile (128x68 f32) | per-wave p rows. 12 bisect + 3 Newton.

#define NBATCH 16
#define NSEQ   2048
#define DHEAD  64
#define OUT_OFF (NBATCH * NSEQ * DHEAD)   // out first, attn second
#define INV_A    3.3333333f               // 1/(alpha-1)
#define INV_A_M1 2.3333333f               // INV_A - 1
#define TK   128                          // K-tile rows in LDS
#define PADK 68                           // row stride (floats): 272 B, 16B-aligned

__device__ __forceinline__ float fast_log2(float x) {
    return __builtin_amdgcn_logf(x);
}
__device__ __forceinline__ float fast_exp2(float x) {
    return __builtin_amdgcn_exp2f(x);
}

__global__ __launch_bounds__(256) void entmax_attn_kernel(
    const float* __restrict__ Q, const float* __restrict__ K,
    const float* __restrict__ V, float* __restrict__ Out)
{
    // union: phase 1 uses smem as K tile (128*68 = 8704 f), phase 2/3 as p rows (4*2048 = 8192 f)
    __shared__ __align__(16) float smem[TK * PADK];
    __shared__ __align__(16) float q_lds[8][DHEAD];
    float (*p_lds)[NSEQ] = (float (*)[NSEQ])smem;

    const int tid  = threadIdx.x;
    const int w    = tid >> 6;        // wave 0..3
    const int lane = tid & 63;

    // XCD pinning: batch b -> XCD b%8 (K/V of a batch = 1 MB, L2-resident)
    const int i   = blockIdx.x;       // 0..4095
    const int xcd = i & 7;
    const int j2  = i >> 3;           // 0..511
    const int b   = xcd + 8 * (j2 & 1);
    const int rb  = j2 >> 1;          // 0..255
    const int n0  = rb * 8;           // block covers q rows n0..n0+7

    const float* Kb = K + (size_t)b * NSEQ * DHEAD;
    const float* Vb = V + (size_t)b * NSEQ * DHEAD;

    // stage the block's 8 q rows (512 floats = 128 float4)
    if (tid < 128) {
        const int r = tid >> 4, g = tid & 15;
        ((float4*)q_lds[r])[g] =
            ((const float4*)(Q + ((size_t)b * NSEQ + (size_t)(n0 + r)) * DHEAD))[g];
    }

    // ---------------- phase 1: scores, K tiled through LDS ----------------
    // wave w owns q rows n0+2w, n0+2w+1; lane owns m = j*64+lane, j=0..31.
    float s[2][32];
    const float* q0p = q_lds[w * 2 + 0];
    const float* q1p = q_lds[w * 2 + 1];

    #pragma unroll 1
    for (int t = 0; t < NSEQ / TK; ++t) {
        __syncthreads();   // previous tile fully consumed (also covers q staging on t=0)
        // stage K tile: 2048 float4s, 8 per thread; global reads fully coalesced
        #pragma unroll
        for (int rep = 0; rep < 8; ++rep) {
            const int f = tid + rep * 256;
            const int m = f >> 4, g = f & 15;
            const float4 kv = ((const float4*)(Kb + (size_t)(t * TK + m) * DHEAD))[g];
            *(float4*)&smem[m * PADK + 4 * g] = kv;
        }
        __syncthreads();

        const float* kr0 = &smem[lane * PADK];          // m = t*128 + lane
        const float* kr1 = &smem[(64 + lane) * PADK];   // m = t*128 + 64 + lane
        float a00 = 0.f, a01 = 0.f, a10 = 0.f, a11 = 0.f;
        #pragma unroll
        for (int g = 0; g < 16; ++g) {
            const float4 qa = *(const float4*)&q0p[4 * g];   // broadcast (uniform addr)
            const float4 qb = *(const float4*)&q1p[4 * g];   // broadcast
            const float4 k0 = *(const float4*)&kr0[4 * g];   // b128, 8-phase floor
            const float4 k1 = *(const float4*)&kr1[4 * g];
            a00 += qa.x * k0.x + qa.y * k0.y + qa.z * k0.z + qa.w * k0.w;
            a01 += qa.x * k1.x + qa.y * k1.y + qa.z * k1.z + qa.w * k1.w;
            a10 += qb.x * k0.x + qb.y * k0.y + qb.z * k0.z + qb.w * k0.w;
            a11 += qb.x * k1.x + qb.y * k1.y + qb.z * k1.z + qb.w * k1.w;
        }
        s[0][2 * t]     = a00 * 0.125f;
        s[0][2 * t + 1] = a01 * 0.125f;
        s[1][2 * t]     = a10 * 0.125f;
        s[1][2 * t + 1] = a11 * 0.125f;
    }
    __syncthreads();   // K region now free -> becomes p_lds

    // ---------------- phase 2+3 per q-row ----------------
    const int msub = lane >> 4;
    const int d4   = lane & 15;

    #pragma unroll
    for (int r = 0; r < 2; ++r) {
        float* sr = s[r];
        const int n = n0 + w * 2 + r;

        // row max (butterfly -> bitwise-identical in all lanes)
        float mx = sr[0];
        #pragma unroll
        for (int j = 1; j < 32; ++j) mx = fmaxf(mx, sr[j]);
        #pragma unroll
        for (int off = 32; off >= 1; off >>= 1) mx = fmaxf(mx, __shfl_xor(mx, off, 64));
        #pragma unroll
        for (int j = 0; j < 32; ++j) sr[j] -= mx;

        // bisection: root of sum(max(x-tau,0)^INV_A) = 1 in [-1, -1e-6]
        float lo = -1.0f, hi = -1e-6f;
        #pragma unroll 1
        for (int it = 0; it < 12; ++it) {
            const float tau = 0.5f * (lo + hi);
            float S = 0.f;
            #pragma unroll
            for (int j = 0; j < 32; ++j) {
                const float t = sr[j] - tau;
                const float p = fast_exp2(INV_A * fast_log2(t));
                S += (t > 0.f) ? p : 0.f;
            }
            #pragma unroll
            for (int off = 32; off >= 1; off >>= 1) S += __shfl_xor(S, off, 64);
            if (S > 1.f) lo = tau; else hi = tau;   // uniform across wave
        }

        // Newton polish from left bracket (monotone-safe, clamped)
        float tau = lo;
        #pragma unroll 1
        for (int it = 0; it < 3; ++it) {
            float S1 = 0.f, S2 = 0.f;
            #pragma unroll
            for (int j = 0; j < 32; ++j) {
                const float t  = sr[j] - tau;
                const float l2 = fast_log2(t);
                const float p  = fast_exp2(INV_A * l2);
                const float pd = fast_exp2(INV_A_M1 * l2);
                const bool pos = (t > 0.f);
                S1 += pos ? p  : 0.f;
                S2 += pos ? pd : 0.f;
            }
            #pragma unroll
            for (int off = 32; off >= 1; off >>= 1) {
                S1 += __shfl_xor(S1, off, 64);
                S2 += __shfl_xor(S2, off, 64);
            }
            tau += (S1 - 1.f) / (INV_A * S2);
            tau = fmaxf(fminf(tau, hi), lo);
        }

        // final probabilities + sum
        float S = 0.f;
        #pragma unroll
        for (int j = 0; j < 32; ++j) {
            const float t = sr[j] - tau;
            const float p = (t > 0.f) ? fast_exp2(INV_A * fast_log2(t)) : 0.f;
            sr[j] = p;
            S += p;
        }
        #pragma unroll
        for (int off = 32; off >= 1; off >>= 1) S += __shfl_xor(S, off, 64);
        const float rnorm = 1.f / (S + 1e-12f);

        // write attn row + stash p in LDS for the PV pass
        float* attn_row = Out + OUT_OFF + ((size_t)b * NSEQ + n) * NSEQ;
        #pragma unroll
        for (int j = 0; j < 32; ++j) {
            const float pv = sr[j] * rnorm;
            attn_row[j * 64 + lane] = pv;
            p_lds[w][j * 64 + lane] = pv;
        }
        // (same-wave LDS write->read: compiler inserts lgkmcnt wait)

        // PV: lane = msub*16 + d4; p via broadcast float4, V coalesced b128
        float4 acc = make_float4(0.f, 0.f, 0.f, 0.f);
        #pragma unroll 2
        for (int m0 = 0; m0 < NSEQ; m0 += 16) {
            const float4 p4 = *(const float4*)&p_lds[w][m0 + 4 * msub];
            const float* pf = (const float*)&p4;
            #pragma unroll
            for (int c = 0; c < 4; ++c) {
                const float4 vv =
                    *(const float4*)(Vb + (size_t)(m0 + 4 * msub + c) * DHEAD + 4 * d4);
                acc.x += pf[c] * vv.x;
                acc.y += pf[c] * vv.y;
                acc.z += pf[c] * vv.z;
                acc.w += pf[c] * vv.w;
            }
        }
        #pragma unroll
        for (int off = 16; off <= 32; off <<= 1) {
            acc.x += __shfl_xor(acc.x, off, 64);
            acc.y += __shfl_xor(acc.y, off, 64);
            acc.z += __shfl_xor(acc.z, off, 64);
            acc.w += __shfl_xor(acc.w, off, 64);
        }
        if (msub == 0) {
            *(float4*)(Out + ((size_t)b * NSEQ + n) * DHEAD + 4 * d4) = acc;
        }
    }
}

extern "C" void kernel_launch(void* const* d_in, const int* in_sizes, int n_in,
                              void* d_out, int out_size, void* d_ws, size_t ws_size,
                              hipStream_t stream) {
    const float* q = (const float*)d_in[0];
    const float* k = (const float*)d_in[1];
    const float* v = (const float*)d_in[2];
    float* out = (float*)d_out;
    (void)in_sizes; (void)n_in; (void)out_size; (void)d_ws; (void)ws_size;
    dim3 grid(4096), block(256);
    hipLaunchKernelGGL(entmax_attn_kernel, grid, block, 0, stream, q, k, v, out);
}